// Round 15
// baseline (271.433 us; speedup 1.0000x reference)
//
#include <hip/hip_runtime.h>
#include <hip/hip_bf16.h>

// SPRGNN: 2-layer GraphConv GNN forward. CSR counting-sort build (LDS atomics
// only), f16 activation storage, fused gather+MFMA convs, f32 accumulate.
// N=100000, E=1200000, G=1000.
//
// R15: agg2 fused into conv2 -> k_fused2 (gather-sum h2 slices in f32 regs,
// f16 A-frags, 4-K-step MFMA). Deletes k_agg + k_conv_mfma + agg2B (25.6MB
// round-trip + one launch). Identical rounding path -> same absmax.
// Profiling note (R14): harness ws re-poison (fillBufferAligned, 268MB,
// ~45us) now tops the profile; it is outside our control.

#define NGRAPHS 1000
#define SCAN_CHUNK 4096
#define EPB 4096          // edges per block in passes A/C
#define SRCMASK 0x1FFFF

typedef _Float16 f16x8 __attribute__((ext_vector_type(8)));
typedef float f32x4 __attribute__((ext_vector_type(4)));

// ---------------------------------------------- pass A: per-block bucket hist
__global__ __launch_bounds__(256) void k_bcount(const int* __restrict__ dst,
                                                int* __restrict__ cnt,
                                                int nE, int nbuck)
{
    __shared__ int h[512];
    int t = threadIdx.x;
    for (int i = t; i < nbuck; i += 256) h[i] = 0;
    __syncthreads();
    int base = blockIdx.x * EPB;
#pragma unroll
    for (int q = 0; q < 16; ++q) {
        int e = base + q * 256 + t;
        if (e < nE) atomicAdd(&h[dst[e] >> 8], 1);
    }
    __syncthreads();
    int* out = cnt + (size_t)blockIdx.x * nbuck;
    for (int i = t; i < nbuck; i += 256) out[i] = h[i];
}

// ------------------------- pass B: exclusive scan of cnt in (bucket,blk) order
__global__ __launch_bounds__(256) void k_pscan_part(const int* __restrict__ cnt,
                                                    int* __restrict__ bsum,
                                                    int L, int nbuck, int nblka)
{
    __shared__ int s[256];
    int t = threadIdx.x;
    int beg = blockIdx.x * SCAN_CHUNK + t * 16;
    int sum = 0;
#pragma unroll
    for (int q = 0; q < 16; ++q) {
        int i = beg + q;
        if (i < L) {
            int b = i / nblka, k = i - b * nblka;
            sum += cnt[(size_t)k * nbuck + b];
        }
    }
    s[t] = sum;
    __syncthreads();
    for (int off = 128; off > 0; off >>= 1) {
        if (t < off) s[t] += s[t + off];
        __syncthreads();
    }
    if (t == 0) bsum[blockIdx.x] = s[0];
}

__global__ __launch_bounds__(64) void k_scan_mid(const int* __restrict__ bsum,
                                                 int* __restrict__ boffs,
                                                 int* __restrict__ row_ptr,
                                                 int B, int n)
{
    if (threadIdx.x == 0) {
        int run = 0;
        for (int b = 0; b < B; ++b) {
            boffs[b] = run;
            run += bsum[b];
        }
        row_ptr[n] = run;
    }
}

__global__ __launch_bounds__(256) void k_pscan_apply(const int* __restrict__ cnt,
                                                     const int* __restrict__ boffs,
                                                     int* __restrict__ offs_flat,
                                                     int L, int nbuck, int nblka)
{
    __shared__ int s[256];
    int t = threadIdx.x;
    int beg = blockIdx.x * SCAN_CHUNK + t * 16;
    int v[16];
    int sum = 0;
#pragma unroll
    for (int q = 0; q < 16; ++q) {
        int i = beg + q;
        if (i < L) {
            int b = i / nblka, k = i - b * nblka;
            v[q] = cnt[(size_t)k * nbuck + b];
        } else v[q] = 0;
        sum += v[q];
    }
    s[t] = sum;
    __syncthreads();
    for (int off = 1; off < 256; off <<= 1) {
        int x2 = (t >= off) ? s[t - off] : 0;
        __syncthreads();
        s[t] += x2;
        __syncthreads();
    }
    int base = boffs[blockIdx.x] + ((t == 0) ? 0 : s[t - 1]);
#pragma unroll
    for (int q = 0; q < 16; ++q) {
        int i = beg + q;
        if (i < L) {
            offs_flat[i] = base;
            base += v[q];
        }
    }
}

// ---------------------- pass C: partition edges into buckets (LDS cursors)
// payload: (dst&255)<<24 | code<<17 | src  (8+7+17 = 32 bits exactly)
__global__ __launch_bounds__(256) void k_bpart(
    const int* __restrict__ src, const int* __restrict__ dst,
    const int* __restrict__ x, const int* __restrict__ offs_flat,
    unsigned* __restrict__ part, int nE, int nblka)
{
    __shared__ int h[512];
    int t = threadIdx.x;
    for (int i = t; i < 512; i += 256) h[i] = 0;
    __syncthreads();
    int base = blockIdx.x * EPB;
#pragma unroll
    for (int q = 0; q < 16; ++q) {
        int e = base + q * 256 + t;
        if (e < nE) {
            int d = dst[e];
            int b = d >> 8;
            int r = atomicAdd(&h[b], 1);
            int s = src[e];
            int2 xv = *(const int2*)(x + 2 * (size_t)s);
            unsigned code = (unsigned)((xv.x << 3) | (xv.y & 7));
            unsigned payload = ((unsigned)(d & 255) << 24) | (code << 17) | (unsigned)s;
            part[offs_flat[(size_t)b * nblka + blockIdx.x] + r] = payload;
        }
    }
}

// ------------- pass D: per-bucket CSR finalize (block = bucket of <=256 nodes)
__global__ __launch_bounds__(256) void k_bfinal(
    const unsigned* __restrict__ part, const int* __restrict__ offs_flat,
    int* __restrict__ row_ptr, int* __restrict__ sorted,
    int n, int nbuck, int nblka, int nE)
{
    __shared__ int h[256];
    __shared__ int cur[256];
    int b = blockIdx.x;
    int t = threadIdx.x;
    int ebeg = offs_flat[(size_t)b * nblka];
    int eend = (b + 1 < nbuck) ? offs_flat[(size_t)(b + 1) * nblka] : nE;

    h[t] = 0;
    __syncthreads();
    for (int e = ebeg + t; e < eend; e += 256)
        atomicAdd(&h[part[e] >> 24], 1);
    __syncthreads();
    int myv = h[t];
    for (int off = 1; off < 256; off <<= 1) {
        int x2 = (t >= off) ? h[t - off] : 0;
        __syncthreads();
        h[t] += x2;
        __syncthreads();
    }
    int excl = h[t] - myv;
    int node = b * 256 + t;
    if (node < n) row_ptr[node] = ebeg + excl;
    cur[t] = ebeg + excl;
    __syncthreads();
    for (int e = ebeg + t; e < eend; e += 256) {
        unsigned u = part[e];
        int r = atomicAdd(&cur[u >> 24], 1);
        sorted[r] = (int)(u & 0xFFFFFFu);
    }
}

// ------------------------------------------ h1 table: one row per input combo
__global__ __launch_bounds__(128) void k_table(
    const float* __restrict__ shape_emb, const float* __restrict__ color_emb,
    const float* __restrict__ W_pre, const float* __restrict__ b_pre,
    _Float16* __restrict__ table)   // [128][32]
{
    int c = threadIdx.x;            // code
    int si = c >> 3, ci = c & 7;
    float in[16];
#pragma unroll
    for (int k = 0; k < 8; ++k) in[k] = shape_emb[si * 8 + k];
#pragma unroll
    for (int k = 0; k < 8; ++k) in[8 + k] = color_emb[ci * 8 + k];
    float acc[32];
#pragma unroll
    for (int j = 0; j < 32; ++j) acc[j] = b_pre[j];
#pragma unroll
    for (int k = 0; k < 16; ++k) {
        float v = in[k];
#pragma unroll
        for (int j = 0; j < 32; ++j) acc[j] += W_pre[j * 16 + k] * v;
    }
#pragma unroll
    for (int g = 0; g < 4; ++g) {
        f16x8 o;
#pragma unroll
        for (int q = 0; q < 8; ++q) o[q] = (_Float16)fmaxf(acc[g * 8 + q], 0.f);
        *(f16x8*)(table + (size_t)c * 32 + g * 8) = o;
    }
}

// --------------------------- fused conv1: table-agg + table-root + MFMA
__global__ __launch_bounds__(256) void k_fused1(
    const int* __restrict__ row_ptr, const int* __restrict__ sorted,
    const int* __restrict__ x, const _Float16* __restrict__ table,
    const float* __restrict__ W_rel, const float* __restrict__ b_rel,
    const float* __restrict__ W_root, _Float16* __restrict__ out, int n)
{
    __shared__ _Float16 tab[128 * 32];
    int t = threadIdx.x;
    for (int i = t * 8; i < 128 * 32; i += 2048)
        *(f16x8*)(tab + i) = *(const f16x8*)(table + i);

    int lane = t & 63;
    int w = t >> 6;
    int col = lane & 15;
    int krow = lane >> 4;

    f16x8 B[2][4];
#pragma unroll
    for (int ks = 0; ks < 2; ++ks) {
#pragma unroll
        for (int ct = 0; ct < 4; ++ct) {
            int j = ct * 16 + col;
            const float* srcw = (ks == 0 ? W_rel : W_root) + (size_t)j * 32 + krow * 8;
            float4 w0 = *(const float4*)(srcw);
            float4 w1 = *(const float4*)(srcw + 4);
            f16x8 bb;
            bb[0] = (_Float16)w0.x; bb[1] = (_Float16)w0.y;
            bb[2] = (_Float16)w0.z; bb[3] = (_Float16)w0.w;
            bb[4] = (_Float16)w1.x; bb[5] = (_Float16)w1.y;
            bb[6] = (_Float16)w1.z; bb[7] = (_Float16)w1.w;
            B[ks][ct] = bb;
        }
        __builtin_amdgcn_sched_barrier(0);
    }
    float bias[4];
#pragma unroll
    for (int ct = 0; ct < 4; ++ct) bias[ct] = b_rel[ct * 16 + col];

    __syncthreads();

    int nodebase = blockIdx.x * 128 + w * 32;
    f32x4 acc[2][4];
#pragma unroll
    for (int nt = 0; nt < 2; ++nt)
#pragma unroll
        for (int ct = 0; ct < 4; ++ct) acc[nt][ct] = (f32x4){0.f, 0.f, 0.f, 0.f};

#pragma unroll
    for (int nt = 0; nt < 2; ++nt) {
        int i = nodebase + nt * 16 + col;
        int iC = min(i, n - 1);
        int e0 = row_ptr[iC];
        int e1 = (i < n) ? row_ptr[iC + 1] : e0;

        float a[8] = {0, 0, 0, 0, 0, 0, 0, 0};
        int e = e0;
        for (; e + 2 <= e1; e += 2) {
            int c0 = sorted[e] >> 17;
            int c1 = sorted[e + 1] >> 17;
            f16x8 r0 = *(const f16x8*)(tab + c0 * 32 + krow * 8);
            f16x8 r1 = *(const f16x8*)(tab + c1 * 32 + krow * 8);
#pragma unroll
            for (int q = 0; q < 8; ++q) a[q] += (float)r0[q] + (float)r1[q];
        }
        if (e < e1) {
            int c0 = sorted[e] >> 17;
            f16x8 r0 = *(const f16x8*)(tab + c0 * 32 + krow * 8);
#pragma unroll
            for (int q = 0; q < 8; ++q) a[q] += (float)r0[q];
        }
        f16x8 Aagg;
#pragma unroll
        for (int q = 0; q < 8; ++q) Aagg[q] = (_Float16)a[q];

        int2 xv = *(const int2*)(x + 2 * (size_t)iC);
        int code = (xv.x << 3) | (xv.y & 7);
        f16x8 Aroot = *(const f16x8*)(tab + code * 32 + krow * 8);

#pragma unroll
        for (int ct = 0; ct < 4; ++ct)
            acc[nt][ct] = __builtin_amdgcn_mfma_f32_16x16x32_f16(
                Aagg, B[0][ct], acc[nt][ct], 0, 0, 0);
#pragma unroll
        for (int ct = 0; ct < 4; ++ct)
            acc[nt][ct] = __builtin_amdgcn_mfma_f32_16x16x32_f16(
                Aroot, B[1][ct], acc[nt][ct], 0, 0, 0);
    }

#pragma unroll
    for (int nt = 0; nt < 2; ++nt) {
#pragma unroll
        for (int r = 0; r < 4; ++r) {
            int node = nodebase + nt * 16 + krow * 4 + r;
            if (node < n) {
#pragma unroll
                for (int ct = 0; ct < 4; ++ct) {
                    float v = acc[nt][ct][r] + bias[ct];
                    out[(size_t)node * 64 + ct * 16 + col] = (_Float16)fmaxf(v, 0.f);
                }
            }
        }
    }
}

// ------------- fused conv2: global gather-agg + root + MFMA (h3 = out)
// out[i][:] = relu(b + Wrel2 @ agg2[i] + Wroot2 @ h2[i]),
//   agg2[i] = sum_e h2[src(e)].  Lane (col,krow) gathers the two 8-ch slices
//   (krow*8 and 32+krow*8) of each neighbor row in f32, converts to f16
//   A-frags; B frags: ks 0,1 = W_rel2, ks 2,3 = W_root2. Same rounding path
//   as the former k_agg+k_conv_mfma pair -> identical output.
__global__ __launch_bounds__(256) void k_fused2(
    const int* __restrict__ row_ptr, const int* __restrict__ sorted,
    const _Float16* __restrict__ h2,
    const float* __restrict__ W_rel, const float* __restrict__ b_rel,
    const float* __restrict__ W_root, _Float16* __restrict__ out, int n)
{
    int t = threadIdx.x;
    int lane = t & 63;
    int w = t >> 6;
    int col = lane & 15;
    int krow = lane >> 4;

    f16x8 B[4][4];
#pragma unroll
    for (int ks = 0; ks < 4; ++ks) {
#pragma unroll
        for (int ct = 0; ct < 4; ++ct) {
            int j = ct * 16 + col;
            int kb = ks * 32 + krow * 8;
            const float* srcw = (ks < 2)
                ? (W_rel + (size_t)j * 64 + kb)
                : (W_root + (size_t)j * 64 + (kb - 64));
            float4 w0 = *(const float4*)(srcw);
            float4 w1 = *(const float4*)(srcw + 4);
            f16x8 bb;
            bb[0] = (_Float16)w0.x; bb[1] = (_Float16)w0.y;
            bb[2] = (_Float16)w0.z; bb[3] = (_Float16)w0.w;
            bb[4] = (_Float16)w1.x; bb[5] = (_Float16)w1.y;
            bb[6] = (_Float16)w1.z; bb[7] = (_Float16)w1.w;
            B[ks][ct] = bb;
        }
        __builtin_amdgcn_sched_barrier(0);
    }
    float bias[4];
#pragma unroll
    for (int ct = 0; ct < 4; ++ct) bias[ct] = b_rel[ct * 16 + col];

    int nodebase = blockIdx.x * 128 + w * 32;
    f32x4 acc[2][4];
#pragma unroll
    for (int nt = 0; nt < 2; ++nt)
#pragma unroll
        for (int ct = 0; ct < 4; ++ct) acc[nt][ct] = (f32x4){0.f, 0.f, 0.f, 0.f};

#pragma unroll
    for (int nt = 0; nt < 2; ++nt) {
        int i = nodebase + nt * 16 + col;
        int iC = min(i, n - 1);
        int e0 = row_ptr[iC];
        int e1 = (i < n) ? row_ptr[iC + 1] : e0;

        // gather-sum the two 8-ch slices of neighbor rows (f32 accum)
        float a0[8] = {0, 0, 0, 0, 0, 0, 0, 0};
        float a1[8] = {0, 0, 0, 0, 0, 0, 0, 0};
        const _Float16* hp0 = h2 + krow * 8;
        const _Float16* hp1 = h2 + 32 + krow * 8;
        int e = e0;
        for (; e + 2 <= e1; e += 2) {
            int s0 = sorted[e] & SRCMASK;
            int s1 = sorted[e + 1] & SRCMASK;
            f16x8 r00 = *(const f16x8*)(hp0 + (size_t)s0 * 64);
            f16x8 r01 = *(const f16x8*)(hp1 + (size_t)s0 * 64);
            f16x8 r10 = *(const f16x8*)(hp0 + (size_t)s1 * 64);
            f16x8 r11 = *(const f16x8*)(hp1 + (size_t)s1 * 64);
#pragma unroll
            for (int q = 0; q < 8; ++q) {
                a0[q] += (float)r00[q] + (float)r10[q];
                a1[q] += (float)r01[q] + (float)r11[q];
            }
        }
        if (e < e1) {
            int s0 = sorted[e] & SRCMASK;
            f16x8 r00 = *(const f16x8*)(hp0 + (size_t)s0 * 64);
            f16x8 r01 = *(const f16x8*)(hp1 + (size_t)s0 * 64);
#pragma unroll
            for (int q = 0; q < 8; ++q) {
                a0[q] += (float)r00[q];
                a1[q] += (float)r01[q];
            }
        }
        f16x8 Aagg0, Aagg1;
#pragma unroll
        for (int q = 0; q < 8; ++q) {
            Aagg0[q] = (_Float16)a0[q];
            Aagg1[q] = (_Float16)a1[q];
        }
        // root slices straight from h2
        f16x8 Aroot0 = *(const f16x8*)(h2 + (size_t)iC * 64 + krow * 8);
        f16x8 Aroot1 = *(const f16x8*)(h2 + (size_t)iC * 64 + 32 + krow * 8);

#pragma unroll
        for (int ct = 0; ct < 4; ++ct)
            acc[nt][ct] = __builtin_amdgcn_mfma_f32_16x16x32_f16(
                Aagg0, B[0][ct], acc[nt][ct], 0, 0, 0);
#pragma unroll
        for (int ct = 0; ct < 4; ++ct)
            acc[nt][ct] = __builtin_amdgcn_mfma_f32_16x16x32_f16(
                Aagg1, B[1][ct], acc[nt][ct], 0, 0, 0);
#pragma unroll
        for (int ct = 0; ct < 4; ++ct)
            acc[nt][ct] = __builtin_amdgcn_mfma_f32_16x16x32_f16(
                Aroot0, B[2][ct], acc[nt][ct], 0, 0, 0);
#pragma unroll
        for (int ct = 0; ct < 4; ++ct)
            acc[nt][ct] = __builtin_amdgcn_mfma_f32_16x16x32_f16(
                Aroot1, B[3][ct], acc[nt][ct], 0, 0, 0);
    }

#pragma unroll
    for (int nt = 0; nt < 2; ++nt) {
#pragma unroll
        for (int r = 0; r < 4; ++r) {
            int node = nodebase + nt * 16 + krow * 4 + r;
            if (node < n) {
#pragma unroll
                for (int ct = 0; ct < 4; ++ct) {
                    float v = acc[nt][ct][r] + bias[ct];
                    out[(size_t)node * 64 + ct * 16 + col] = (_Float16)fmaxf(v, 0.f);
                }
            }
        }
    }
}

// ------------------------------------------- pool (block per graph) + classifier
__global__ __launch_bounds__(256) void k_pool_cls(
    const _Float16* __restrict__ h3, const int* __restrict__ batch,
    const float* __restrict__ W_cls, const float* __restrict__ b_cls,
    float* __restrict__ out, int n)
{
    __shared__ float part[4][64];
    __shared__ float pool[64];
    __shared__ int range[2];
    int g = blockIdx.x;
    int t = threadIdx.x;

    if (t < 2) {
        int key = g + t;
        int lo = 0, hi = n;
        while (lo < hi) {
            int mid = (lo + hi) >> 1;
            if (batch[mid] < key) lo = mid + 1; else hi = mid;
        }
        range[t] = lo;
    }
    __syncthreads();
    int start = range[0], end = range[1];

    int j = t & 63;
    int sub = t >> 6;
    float local = 0.f;
    for (int i = start + sub; i < end; i += 4)
        local += (float)h3[(size_t)i * 64 + j];
    part[sub][j] = local;
    __syncthreads();

    if (t < 64) {
        float cnt = (float)(end - start);
        float inv = 1.0f / fmaxf(cnt, 1.0f);
        pool[t] = (part[0][t] + part[1][t] + part[2][t] + part[3][t]) * inv;
    }
    __syncthreads();

    if (t < 10) {
        float acc = b_cls[t];
#pragma unroll
        for (int k = 0; k < 64; ++k) acc += W_cls[t * 64 + k] * pool[k];
        out[(size_t)g * 10 + t] = acc;
    }
}

// ---------------------------------------------------------------- launch
extern "C" void kernel_launch(void* const* d_in, const int* in_sizes, int n_in,
                              void* d_out, int out_size, void* d_ws, size_t ws_size,
                              hipStream_t stream)
{
    const int* x        = (const int*)d_in[0];
    const int* ei       = (const int*)d_in[1];
    const int* batch    = (const int*)d_in[2];
    const float* shape_emb = (const float*)d_in[4];
    const float* color_emb = (const float*)d_in[5];
    const float* W_pre   = (const float*)d_in[6];
    const float* b_pre   = (const float*)d_in[7];
    const float* W_rel1  = (const float*)d_in[8];
    const float* b_rel1  = (const float*)d_in[9];
    const float* W_root1 = (const float*)d_in[10];
    const float* W_rel2  = (const float*)d_in[11];
    const float* b_rel2  = (const float*)d_in[12];
    const float* W_root2 = (const float*)d_in[13];
    const float* W_cls   = (const float*)d_in[14];
    const float* b_cls   = (const float*)d_in[15];

    const int n  = in_sizes[0] / 2;   // 100000
    const int nE = in_sizes[1] / 2;   // 1200000
    const int G  = NGRAPHS;
    const int* src = ei;
    const int* dst = ei + nE;

    const int NBUCK = (n + 255) >> 8;              // 391
    const int NBLKA = (nE + EPB - 1) / EPB;        // 293
    const int L     = NBUCK * NBLKA;               // ~114563
    const int SBL   = (L + SCAN_CHUNK - 1) / SCAN_CHUNK;  // 28

    // workspace (f16 elements), all disjoint:
    //  h2B [n*64] | h3B [n*64] | tabB [128*32]
    //  ints: row_ptr[n+1] | cnt[L] | offs_flat[L] | part[E] | sorted[E]
    //        | bsum[64] | boffs[64]
    _Float16* us = (_Float16*)d_ws;
    _Float16* h2B   = us;
    _Float16* h3B   = us + (size_t)n * 64;
    _Float16* tabB  = us + (size_t)n * 128;
    int* ints      = (int*)(tabB + 128 * 32);
    int* row_ptr   = ints;                       // n+1
    int* cnt       = row_ptr + (n + 1);          // L
    int* offs_flat = cnt + L;                    // L
    unsigned* part = (unsigned*)(offs_flat + L); // E
    int* sorted    = (int*)(part + nE);          // E
    int* bsum      = sorted + nE;                // <=64
    int* boffs     = bsum + 64;                  // <=64

    const int CB = (n + 127) / 128;

    // --- CSR build (LDS-atomic counting sort) + layer-1 table ---
    k_table<<<1, 128, 0, stream>>>(shape_emb, color_emb, W_pre, b_pre, tabB);
    k_bcount<<<NBLKA, 256, 0, stream>>>(dst, cnt, nE, NBUCK);
    k_pscan_part<<<SBL, 256, 0, stream>>>(cnt, bsum, L, NBUCK, NBLKA);
    k_scan_mid<<<1, 64, 0, stream>>>(bsum, boffs, row_ptr, SBL, n);
    k_pscan_apply<<<SBL, 256, 0, stream>>>(cnt, boffs, offs_flat, L, NBUCK, NBLKA);
    k_bpart<<<NBLKA, 256, 0, stream>>>(src, dst, x, offs_flat, part, nE, NBLKA);
    k_bfinal<<<NBUCK, 256, 0, stream>>>(part, offs_flat, row_ptr, sorted,
                                        n, NBUCK, NBLKA, nE);

    // --- forward ---
    k_fused1<<<CB, 256, 0, stream>>>(row_ptr, sorted, x, tabB,
                                     W_rel1, b_rel1, W_root1, h2B, n);
    k_fused2<<<CB, 256, 0, stream>>>(row_ptr, sorted, h2B,
                                     W_rel2, b_rel2, W_root2, h3B, n);
    k_pool_cls<<<G, 256, 0, stream>>>(h3B, batch, W_cls, b_cls, (float*)d_out, n);
}